// Round 1
// baseline (898.182 us; speedup 1.0000x reference)
//
#include <hip/hip_runtime.h>
#include <hip/hip_bf16.h>

typedef __bf16 bf16x8 __attribute__((ext_vector_type(8)));
typedef float f32x4 __attribute__((ext_vector_type(4)));
typedef unsigned short u16x8 __attribute__((ext_vector_type(8)));

#define MBY (1ull << 20)
#define LDA 40  // LDS row stride in ushorts (32 data + 8 pad = 80B): 2-way-only bank aliasing

__device__ __forceinline__ unsigned short f2bf(float f) {
  union { float f; unsigned u; } v; v.f = f;
  unsigned r = v.u + 0x7fffu + ((v.u >> 16) & 1u);  // RNE
  return (unsigned short)(r >> 16);
}
__device__ __forceinline__ float bf2f(unsigned short s) {
  union { unsigned u; float f; } v; v.u = ((unsigned)s) << 16;
  return v.f;
}

// ---------------- prep: transpose+convert the 3 big weight matrices to bf16 [n][k]
__global__ void prep_wt_kernel(const float* __restrict__ wx, const float* __restrict__ wy,
                               const float* __restrict__ wo,
                               unsigned short* __restrict__ wxT, unsigned short* __restrict__ wyT,
                               unsigned short* __restrict__ woT) {
  int g = blockIdx.x * 256 + threadIdx.x;      // 262144 per matrix
  int n = g & 511, k = g >> 9;
  const float* src = (blockIdx.y == 0) ? wx : (blockIdx.y == 1) ? wy : wo;
  unsigned short* dst = (blockIdx.y == 0) ? wxT : (blockIdx.y == 1) ? wyT : woT;
  dst[(size_t)n * 512 + k] = f2bf(src[(size_t)k * 512 + n]);
}

// ---------------- GEMM1 (dual): xb_pre = x@w_x + b_x (bf16), yb = gelu_tanh(x@w_y + b_y) (bf16)
__global__ __launch_bounds__(256, 2)
void gemm_dual_kernel(const float* __restrict__ x,
                      const unsigned short* __restrict__ wxT,
                      const unsigned short* __restrict__ wyT,
                      const float* __restrict__ bx, const float* __restrict__ by,
                      unsigned short* __restrict__ xbp, unsigned short* __restrict__ ybuf) {
  __shared__ unsigned short As[128 * LDA];
  __shared__ unsigned short Bs0[128 * LDA];
  __shared__ unsigned short Bs1[128 * LDA];
  const int tid = threadIdx.x;
  const int lane = tid & 63, wv = tid >> 6;
  const int m0 = blockIdx.y * 128;      // grid = (4 n-blocks, 512 m-blocks): n-fastest for A reuse
  const int n0 = blockIdx.x * 128;
  const int srow = tid >> 1;            // staging row 0..127
  const int skq = (tid & 1) << 4;       // staging k offset 0/16
  const int wm = (wv >> 1) << 6, wn = (wv & 1) << 6;
  const int fm = lane & 15, fq = lane >> 4;

  f32x4 acc0[4][4], acc1[4][4];
#pragma unroll
  for (int i = 0; i < 4; ++i)
#pragma unroll
    for (int j = 0; j < 4; ++j) {
      acc0[i][j] = f32x4{0.f, 0.f, 0.f, 0.f};
      acc1[i][j] = f32x4{0.f, 0.f, 0.f, 0.f};
    }

  const float* xg = x + (size_t)(m0 + srow) * 512 + skq;
  const unsigned short* wxg = wxT + (size_t)(n0 + srow) * 512 + skq;
  const unsigned short* wyg = wyT + (size_t)(n0 + srow) * 512 + skq;

  for (int k0 = 0; k0 < 512; k0 += 32) {
    float4 a0 = *(const float4*)(xg + k0);
    float4 a1 = *(const float4*)(xg + k0 + 4);
    float4 a2 = *(const float4*)(xg + k0 + 8);
    float4 a3 = *(const float4*)(xg + k0 + 12);
    u16x8 b00 = *(const u16x8*)(wxg + k0);
    u16x8 b01 = *(const u16x8*)(wxg + k0 + 8);
    u16x8 b10 = *(const u16x8*)(wyg + k0);
    u16x8 b11 = *(const u16x8*)(wyg + k0 + 8);
    u16x8 pa0, pa1;
    pa0[0] = f2bf(a0.x); pa0[1] = f2bf(a0.y); pa0[2] = f2bf(a0.z); pa0[3] = f2bf(a0.w);
    pa0[4] = f2bf(a1.x); pa0[5] = f2bf(a1.y); pa0[6] = f2bf(a1.z); pa0[7] = f2bf(a1.w);
    pa1[0] = f2bf(a2.x); pa1[1] = f2bf(a2.y); pa1[2] = f2bf(a2.z); pa1[3] = f2bf(a2.w);
    pa1[4] = f2bf(a3.x); pa1[5] = f2bf(a3.y); pa1[6] = f2bf(a3.z); pa1[7] = f2bf(a3.w);
    __syncthreads();
    *(u16x8*)&As[srow * LDA + skq] = pa0;
    *(u16x8*)&As[srow * LDA + skq + 8] = pa1;
    *(u16x8*)&Bs0[srow * LDA + skq] = b00;
    *(u16x8*)&Bs0[srow * LDA + skq + 8] = b01;
    *(u16x8*)&Bs1[srow * LDA + skq] = b10;
    *(u16x8*)&Bs1[srow * LDA + skq + 8] = b11;
    __syncthreads();
    bf16x8 af[4], bfr0[4], bfr1[4];
#pragma unroll
    for (int i = 0; i < 4; ++i)
      af[i] = *(const bf16x8*)&As[(wm + i * 16 + fm) * LDA + fq * 8];
#pragma unroll
    for (int j = 0; j < 4; ++j) {
      bfr0[j] = *(const bf16x8*)&Bs0[(wn + j * 16 + fm) * LDA + fq * 8];
      bfr1[j] = *(const bf16x8*)&Bs1[(wn + j * 16 + fm) * LDA + fq * 8];
    }
#pragma unroll
    for (int i = 0; i < 4; ++i)
#pragma unroll
      for (int j = 0; j < 4; ++j) {
        acc0[i][j] = __builtin_amdgcn_mfma_f32_16x16x32_bf16(af[i], bfr0[j], acc0[i][j], 0, 0, 0);
        acc1[i][j] = __builtin_amdgcn_mfma_f32_16x16x32_bf16(af[i], bfr1[j], acc1[i][j], 0, 0, 0);
      }
  }
#pragma unroll
  for (int i = 0; i < 4; ++i) {
#pragma unroll
    for (int j = 0; j < 4; ++j) {
      int col = n0 + wn + j * 16 + fm;
      float bxv = bx[col], byv = by[col];
#pragma unroll
      for (int r = 0; r < 4; ++r) {
        int row = m0 + wm + i * 16 + fq * 4 + r;
        size_t idx = (size_t)row * 512 + col;
        float v = acc0[i][j][r] + bxv;
        xbp[idx] = f2bf(v);
        float z = acc1[i][j][r] + byv;
        float zc = z + 0.044715f * z * z * z;
        float th = tanhf(0.7978845608028654f * zc);
        ybuf[idx] = f2bf(0.5f * z * (1.0f + th));
      }
    }
  }
}

// ---------------- conv (TW=4, causal, per-batch) + block-diag gates + a/normed
__global__ __launch_bounds__(256)
void conv_gates_kernel(const unsigned short* __restrict__ xbp,
                       const unsigned char* __restrict__ reset,
                       const float* __restrict__ conv_w, const float* __restrict__ conv_b,
                       const float* __restrict__ a_param,
                       const float* __restrict__ wi, const float* __restrict__ bi,
                       const float* __restrict__ wa, const float* __restrict__ ba,
                       float* __restrict__ a_out, unsigned short* __restrict__ nrm) {
  __shared__ unsigned short xin[67][64];
  __shared__ float xc[64][64];
  __shared__ float wiS[64][64];
  __shared__ float waS[64][64];
  const int tile = blockIdx.x, h = blockIdx.y, b = blockIdx.z;
  const int t0 = tile << 6;
  const int c = threadIdx.x & 63;
  const int tq = threadIdx.x >> 6;
  const int cg = (h << 6) + c;

  for (int r = tq; r < 64; r += 4) {
    wiS[r][c] = wi[((h << 6) + r) * 64 + c];
    waS[r][c] = wa[((h << 6) + r) * 64 + c];
  }
  for (int r = tq; r < 67; r += 4) {
    int t = t0 - 3 + r;
    xin[r][c] = (t >= 0) ? xbp[((size_t)(b * 2048 + t) << 9) + cg] : (unsigned short)0;
  }
  __syncthreads();
  float cw0 = conv_w[cg], cw1 = conv_w[512 + cg], cw2 = conv_w[1024 + cg], cw3 = conv_w[1536 + cg];
  float cb = conv_b[cg];
  for (int u = tq; u < 64; u += 4) {
    xc[u][c] = cb + cw0 * bf2f(xin[u][c]) + cw1 * bf2f(xin[u + 1][c]) +
               cw2 * bf2f(xin[u + 2][c]) + cw3 * bf2f(xin[u + 3][c]);
  }
  __syncthreads();
  float accI[16], accA[16];
  float biv = bi[cg], bav = ba[cg];
#pragma unroll
  for (int i = 0; i < 16; ++i) { accI[i] = biv; accA[i] = bav; }
  for (int j = 0; j < 64; j += 4) {
    float wI0 = wiS[j][c], wI1 = wiS[j + 1][c], wI2 = wiS[j + 2][c], wI3 = wiS[j + 3][c];
    float wA0 = waS[j][c], wA1 = waS[j + 1][c], wA2 = waS[j + 2][c], wA3 = waS[j + 3][c];
#pragma unroll
    for (int i = 0; i < 16; ++i) {
      const float4 x4 = *(const float4*)&xc[(tq << 4) + i][j];  // wave-uniform: LDS broadcast
      accI[i] += x4.x * wI0 + x4.y * wI1 + x4.z * wI2 + x4.w * wI3;
      accA[i] += x4.x * wA0 + x4.y * wA1 + x4.z * wA2 + x4.w * wA3;
    }
  }
  float apv = a_param[cg];
  float sp = (apv > 0.f) ? apv + log1pf(expf(-apv)) : log1pf(expf(apv));  // softplus
#pragma unroll
  for (int i = 0; i < 16; ++i) {
    int tl = (tq << 4) + i;
    int t = t0 + tl;
    float gx = 1.0f / (1.0f + expf(-accI[i]));
    float ga = 1.0f / (1.0f + expf(-accA[i]));
    float la = -8.0f * ga * sp;
    float av = expf(la);
    float mult = sqrtf(fmaxf(-expm1f(2.0f * la), 0.0f));
    if (reset[b * 2048 + t]) { mult = 1.0f; av = 0.0f; }
    float nv = xc[tl][c] * gx * mult;
    size_t idx = ((size_t)(b * 2048 + t) << 9) + cg;
    a_out[idx] = av;
    nrm[idx] = f2bf(nv);
  }
}

// ---------------- chunked linear scan: 32 chunks of 64 steps
__global__ void scan1_kernel(const float* __restrict__ a, const unsigned short* __restrict__ nrm,
                             float* __restrict__ cA, float* __restrict__ cH) {
  int g = blockIdx.x * 256 + threadIdx.x;  // 524288 = 32b * 32k * 512c
  int c = g & 511, k = (g >> 9) & 31, b = g >> 14;
  size_t base = ((size_t)(b * 2048 + k * 64) << 9) + c;
  float A = 1.0f, h = 0.0f;
#pragma unroll 4
  for (int i = 0; i < 64; ++i) {
    float at = a[base + (size_t)i * 512];
    float nt = bf2f(nrm[base + (size_t)i * 512]);
    A *= at;
    h = fmaf(at, h, nt);
  }
  int ci = ((b * 32 + k) << 9) + c;
  cA[ci] = A;
  cH[ci] = h;
}

__global__ void scan2_kernel(const float* __restrict__ cA, const float* __restrict__ cH,
                             const float* __restrict__ h0, float* __restrict__ hinit) {
  int b = blockIdx.x, c = threadIdx.x;  // 32 blocks x 512
  float h = h0[b * 512 + c];
  for (int k = 0; k < 32; ++k) {
    int ci = ((b * 32 + k) << 9) + c;
    hinit[ci] = h;
    h = fmaf(cA[ci], h, cH[ci]);
  }
}

__global__ void scan3_kernel(const float* __restrict__ a, const unsigned short* __restrict__ nrm,
                             const float* __restrict__ hinit, const unsigned short* __restrict__ ybuf,
                             unsigned short* __restrict__ p) {
  int g = blockIdx.x * 256 + threadIdx.x;
  int c = g & 511, k = (g >> 9) & 31, b = g >> 14;
  size_t base = ((size_t)(b * 2048 + k * 64) << 9) + c;
  int ci = ((b * 32 + k) << 9) + c;
  float h = hinit[ci];
#pragma unroll 4
  for (int i = 0; i < 64; ++i) {
    float at = a[base + (size_t)i * 512];
    float nt = bf2f(nrm[base + (size_t)i * 512]);
    h = fmaf(at, h, nt);
    float yv = bf2f(ybuf[base + (size_t)i * 512]);
    p[base + (size_t)i * 512] = f2bf(h * yv);
  }
}

// ---------------- GEMM2: out = p @ w_out + b_out (fp32 out)
__global__ __launch_bounds__(256, 2)
void gemm_out_kernel(const unsigned short* __restrict__ p,
                     const unsigned short* __restrict__ woT,
                     const float* __restrict__ bout, float* __restrict__ out) {
  __shared__ unsigned short As[128 * LDA];
  __shared__ unsigned short Bs[128 * LDA];
  const int tid = threadIdx.x;
  const int lane = tid & 63, wv = tid >> 6;
  const int m0 = blockIdx.y * 128;
  const int n0 = blockIdx.x * 128;
  const int srow = tid >> 1;
  const int skq = (tid & 1) << 4;
  const int wm = (wv >> 1) << 6, wn = (wv & 1) << 6;
  const int fm = lane & 15, fq = lane >> 4;

  f32x4 acc[4][4];
#pragma unroll
  for (int i = 0; i < 4; ++i)
#pragma unroll
    for (int j = 0; j < 4; ++j) acc[i][j] = f32x4{0.f, 0.f, 0.f, 0.f};

  const unsigned short* pg = p + (size_t)(m0 + srow) * 512 + skq;
  const unsigned short* wg = woT + (size_t)(n0 + srow) * 512 + skq;

  for (int k0 = 0; k0 < 512; k0 += 32) {
    u16x8 a0 = *(const u16x8*)(pg + k0);
    u16x8 a1 = *(const u16x8*)(pg + k0 + 8);
    u16x8 b0 = *(const u16x8*)(wg + k0);
    u16x8 b1 = *(const u16x8*)(wg + k0 + 8);
    __syncthreads();
    *(u16x8*)&As[srow * LDA + skq] = a0;
    *(u16x8*)&As[srow * LDA + skq + 8] = a1;
    *(u16x8*)&Bs[srow * LDA + skq] = b0;
    *(u16x8*)&Bs[srow * LDA + skq + 8] = b1;
    __syncthreads();
    bf16x8 af[4], bfr[4];
#pragma unroll
    for (int i = 0; i < 4; ++i)
      af[i] = *(const bf16x8*)&As[(wm + i * 16 + fm) * LDA + fq * 8];
#pragma unroll
    for (int j = 0; j < 4; ++j)
      bfr[j] = *(const bf16x8*)&Bs[(wn + j * 16 + fm) * LDA + fq * 8];
#pragma unroll
    for (int i = 0; i < 4; ++i)
#pragma unroll
      for (int j = 0; j < 4; ++j)
        acc[i][j] = __builtin_amdgcn_mfma_f32_16x16x32_bf16(af[i], bfr[j], acc[i][j], 0, 0, 0);
  }
#pragma unroll
  for (int i = 0; i < 4; ++i) {
#pragma unroll
    for (int j = 0; j < 4; ++j) {
      int col = n0 + wn + j * 16 + fm;
      float bv = bout[col];
#pragma unroll
      for (int r = 0; r < 4; ++r) {
        int row = m0 + wm + i * 16 + fq * 4 + r;
        out[(size_t)row * 512 + col] = acc[i][j][r] + bv;
      }
    }
  }
}

extern "C" void kernel_launch(void* const* d_in, const int* in_sizes, int n_in,
                              void* d_out, int out_size, void* d_ws, size_t ws_size,
                              hipStream_t stream) {
  const float* x             = (const float*)d_in[0];
  const unsigned char* reset = (const unsigned char*)d_in[1];
  const float* h0            = (const float*)d_in[2];
  const float* w_x           = (const float*)d_in[3];
  const float* b_x           = (const float*)d_in[4];
  const float* w_y           = (const float*)d_in[5];
  const float* b_y           = (const float*)d_in[6];
  const float* conv_w        = (const float*)d_in[7];
  const float* conv_b        = (const float*)d_in[8];
  const float* a_param       = (const float*)d_in[9];
  const float* wi            = (const float*)d_in[10];
  const float* bi            = (const float*)d_in[11];
  const float* wa            = (const float*)d_in[12];
  const float* ba            = (const float*)d_in[13];
  const float* b_out         = (const float*)d_in[15];
  // w_out = d_in[14] used by prep

  char* ws = (char*)d_ws;
  unsigned short* xbp  = (unsigned short*)(ws);               // 64MB bf16, reused as p after conv_gates
  unsigned short* ybuf = (unsigned short*)(ws + 64 * MBY);    // 64MB bf16
  float* a_arr         = (float*)(ws + 128 * MBY);            // 128MB fp32 (compounding-sensitive)
  unsigned short* nrm  = (unsigned short*)(ws + 256 * MBY);   // 64MB bf16
  float* cA            = (float*)(ws + 320 * MBY);            // 2MB
  float* cH            = (float*)(ws + 322 * MBY);            // 2MB
  float* hinit         = (float*)(ws + 324 * MBY);            // 2MB
  unsigned short* wxT  = (unsigned short*)(ws + 326 * MBY);
  unsigned short* wyT  = (unsigned short*)(ws + 326 * MBY + 524288);
  unsigned short* woT  = (unsigned short*)(ws + 327 * MBY);
  unsigned short* p    = xbp;

  hipLaunchKernelGGL(prep_wt_kernel, dim3(1024, 3), dim3(256), 0, stream,
                     (const float*)d_in[3], (const float*)d_in[5], (const float*)d_in[14],
                     wxT, wyT, woT);
  hipLaunchKernelGGL(gemm_dual_kernel, dim3(4, 512), dim3(256), 0, stream,
                     x, wxT, wyT, b_x, b_y, xbp, ybuf);
  hipLaunchKernelGGL(conv_gates_kernel, dim3(32, 8, 32), dim3(256), 0, stream,
                     xbp, reset, conv_w, conv_b, a_param, wi, bi, wa, ba, a_arr, nrm);
  hipLaunchKernelGGL(scan1_kernel, dim3(2048), dim3(256), 0, stream, a_arr, nrm, cA, cH);
  hipLaunchKernelGGL(scan2_kernel, dim3(32), dim3(512), 0, stream, cA, cH, h0, hinit);
  hipLaunchKernelGGL(scan3_kernel, dim3(2048), dim3(256), 0, stream, a_arr, nrm, hinit, ybuf, p);
  hipLaunchKernelGGL(gemm_out_kernel, dim3(4, 512), dim3(256), 0, stream, p, woT, b_out, (float*)d_out);
}

// Round 2
// 764.783 us; speedup vs baseline: 1.1744x; 1.1744x over previous
//
#include <hip/hip_runtime.h>

typedef __bf16 bf16x8 __attribute__((ext_vector_type(8)));
typedef float f32x4 __attribute__((ext_vector_type(4)));
typedef unsigned short u16x8 __attribute__((ext_vector_type(8)));
typedef unsigned short u16x4 __attribute__((ext_vector_type(4)));

#define MBY (1ull << 20)

__device__ __forceinline__ unsigned short f2bf(float f) {
  union { float f; unsigned u; } v; v.f = f;
  unsigned r = v.u + 0x7fffu + ((v.u >> 16) & 1u);  // RNE
  return (unsigned short)(r >> 16);
}
__device__ __forceinline__ float bf2f(unsigned short s) {
  union { unsigned u; float f; } v; v.u = ((unsigned)s) << 16;
  return v.f;
}
// async global->LDS, 16B per lane; lds dest = wave-uniform base + lane*16
__device__ __forceinline__ void gl2lds16(const void* g, void* l) {
  __builtin_amdgcn_global_load_lds(
      (const __attribute__((address_space(1))) unsigned int*)g,
      (__attribute__((address_space(3))) unsigned int*)l, 16, 0, 0);
}

// ---------------- prep: x -> bf16
__global__ void prep_x_kernel(const float* __restrict__ x, unsigned short* __restrict__ xbf) {
  int g = blockIdx.x * 256 + threadIdx.x;   // 8388608 threads, 4 elems each
  float4 v = ((const float4*)x)[g];
  u16x4 o;
  o[0] = f2bf(v.x); o[1] = f2bf(v.y); o[2] = f2bf(v.z); o[3] = f2bf(v.w);
  *(u16x4*)(xbf + (size_t)g * 4) = o;
}

// ---------------- prep: transpose+convert w_x, w_y, w_out to bf16 [n][k]
__global__ void prep_wt_kernel(const float* __restrict__ wx, const float* __restrict__ wy,
                               const float* __restrict__ wo,
                               unsigned short* __restrict__ wxT, unsigned short* __restrict__ wyT,
                               unsigned short* __restrict__ woT) {
  int g = blockIdx.x * 256 + threadIdx.x;
  int n = g & 511, k = g >> 9;
  const float* src = (blockIdx.y == 0) ? wx : (blockIdx.y == 1) ? wy : wo;
  unsigned short* dst = (blockIdx.y == 0) ? wxT : (blockIdx.y == 1) ? wyT : woT;
  dst[(size_t)n * 512 + k] = f2bf(src[(size_t)k * 512 + n]);
}

// ---------------- prep: gate weights -> transposed [h][n][k] hi/lo bf16 split
__global__ void prep_gatew_kernel(const float* __restrict__ wi, const float* __restrict__ wa,
                                  unsigned short* __restrict__ wiTH, unsigned short* __restrict__ wiTL,
                                  unsigned short* __restrict__ waTH, unsigned short* __restrict__ waTL) {
  int g = blockIdx.x * 256 + threadIdx.x;  // 32768
  int j = g & 63, i = (g >> 6) & 63, h = g >> 12;
  size_t src = (size_t)h * 4096 + (size_t)i * 64 + j;
  size_t dst = (size_t)h * 4096 + (size_t)j * 64 + i;
  float v = wi[src];
  unsigned short hh = f2bf(v);
  wiTH[dst] = hh; wiTL[dst] = f2bf(v - bf2f(hh));
  v = wa[src];
  hh = f2bf(v);
  waTH[dst] = hh; waTL[dst] = f2bf(v - bf2f(hh));
}

// ---------------- GEMM1 (dual): xb_pre = x@w_x + b_x ; yb = gelu(x@w_y + b_y)
__global__ __launch_bounds__(256, 2)
void gemm_dual_kernel(const unsigned short* __restrict__ xbf,
                      const unsigned short* __restrict__ wxT,
                      const unsigned short* __restrict__ wyT,
                      const float* __restrict__ bx, const float* __restrict__ by,
                      unsigned short* __restrict__ xbp, unsigned short* __restrict__ ybuf) {
  __shared__ __align__(16) unsigned short As[128 * 32];
  __shared__ __align__(16) unsigned short Bs0[128 * 32];
  __shared__ __align__(16) unsigned short Bs1[128 * 32];
  const int tid = threadIdx.x, lane = tid & 63, wv = tid >> 6;
  const int m0 = blockIdx.y * 128, n0 = blockIdx.x * 128;  // n-fastest grid for A reuse
  const int sr = lane >> 2, sk = (lane & 3) * 8;
  const int wm = (wv >> 1) << 6, wn = (wv & 1) << 6;
  const int fm = lane & 15, fq = lane >> 4;

  f32x4 acc0[4][4], acc1[4][4];
#pragma unroll
  for (int i = 0; i < 4; ++i)
#pragma unroll
    for (int j = 0; j < 4; ++j) {
      acc0[i][j] = f32x4{0.f, 0.f, 0.f, 0.f};
      acc1[i][j] = f32x4{0.f, 0.f, 0.f, 0.f};
    }

  const unsigned short* ga  = xbf + (size_t)(m0 + wv * 32 + sr) * 512 + sk;
  const unsigned short* gb0 = wxT + (size_t)(n0 + wv * 32 + sr) * 512 + sk;
  const unsigned short* gb1 = wyT + (size_t)(n0 + wv * 32 + sr) * 512 + sk;
  unsigned short* lA  = &As [wv * 32 * 32];
  unsigned short* lB0 = &Bs0[wv * 32 * 32];
  unsigned short* lB1 = &Bs1[wv * 32 * 32];

  for (int k0 = 0; k0 < 512; k0 += 32) {
    __syncthreads();
    gl2lds16(ga  + k0,            lA);
    gl2lds16(ga  + k0 + 16 * 512, lA  + 16 * 32);
    gl2lds16(gb0 + k0,            lB0);
    gl2lds16(gb0 + k0 + 16 * 512, lB0 + 16 * 32);
    gl2lds16(gb1 + k0,            lB1);
    gl2lds16(gb1 + k0 + 16 * 512, lB1 + 16 * 32);
    __syncthreads();
    bf16x8 af[4], bfr0[4], bfr1[4];
#pragma unroll
    for (int i = 0; i < 4; ++i)
      af[i] = *(const bf16x8*)&As[(wm + i * 16 + fm) * 32 + fq * 8];
#pragma unroll
    for (int j = 0; j < 4; ++j) {
      bfr0[j] = *(const bf16x8*)&Bs0[(wn + j * 16 + fm) * 32 + fq * 8];
      bfr1[j] = *(const bf16x8*)&Bs1[(wn + j * 16 + fm) * 32 + fq * 8];
    }
#pragma unroll
    for (int i = 0; i < 4; ++i)
#pragma unroll
      for (int j = 0; j < 4; ++j) {
        acc0[i][j] = __builtin_amdgcn_mfma_f32_16x16x32_bf16(af[i], bfr0[j], acc0[i][j], 0, 0, 0);
        acc1[i][j] = __builtin_amdgcn_mfma_f32_16x16x32_bf16(af[i], bfr1[j], acc1[i][j], 0, 0, 0);
      }
  }
#pragma unroll
  for (int i = 0; i < 4; ++i) {
#pragma unroll
    for (int j = 0; j < 4; ++j) {
      int col = n0 + wn + j * 16 + fm;
      float bxv = bx[col], byv = by[col];
#pragma unroll
      for (int r = 0; r < 4; ++r) {
        int row = m0 + wm + i * 16 + fq * 4 + r;
        size_t idx = (size_t)row * 512 + col;
        xbp[idx] = f2bf(acc0[i][j][r] + bxv);
        float z = acc1[i][j][r] + byv;
        float zc = z + 0.044715f * z * z * z;
        float th = tanhf(0.7978845608028654f * zc);
        ybuf[idx] = f2bf(0.5f * z * (1.0f + th));
      }
    }
  }
}

// ---------------- conv (TW=4) + MFMA gate GEMMs (hi/lo bf16 split) + a/normed
#define XP 72  // padded LDS row stride (144B: 16B-aligned rows, 2-way-only bank alias)
__global__ __launch_bounds__(256, 2)
void conv_gates_kernel(const unsigned short* __restrict__ xbp,
                       const unsigned char* __restrict__ reset,
                       const float* __restrict__ conv_w, const float* __restrict__ conv_b,
                       const float* __restrict__ a_param,
                       const unsigned short* __restrict__ wiTH, const unsigned short* __restrict__ wiTL,
                       const unsigned short* __restrict__ waTH, const unsigned short* __restrict__ waTL,
                       const float* __restrict__ bi, const float* __restrict__ ba,
                       float* __restrict__ a_out, unsigned short* __restrict__ nrm) {
  __shared__ __align__(16) unsigned short xin[131 * 64];
  __shared__ __align__(16) unsigned short xcH[128 * XP];
  __shared__ __align__(16) unsigned short xcL[128 * XP];
  const int tile = blockIdx.x, h = blockIdx.y, b = blockIdx.z;
  const int t0 = tile << 7;                 // 128 tokens per block
  const int tid = threadIdx.x, lane = tid & 63, wv = tid >> 6;
  const int c = tid & 63, tq = tid >> 6;
  const int fm = lane & 15, fq = lane >> 4;

  // stage raw xb tile (+3 history rows)
  for (int r = tq; r < 131; r += 4) {
    int t = t0 - 3 + r;
    xin[r * 64 + c] = (t >= 0) ? xbp[((size_t)(b * 2048 + t) << 9) + (h << 6) + c] : (unsigned short)0;
  }
  __syncthreads();
  // conv in fp32, split into hi/lo bf16 planes
  {
    float cw0 = conv_w[(h << 6) + c], cw1 = conv_w[512 + (h << 6) + c];
    float cw2 = conv_w[1024 + (h << 6) + c], cw3 = conv_w[1536 + (h << 6) + c];
    float cb = conv_b[(h << 6) + c];
    int base = tq * 32;
    float X0 = bf2f(xin[(base + 0) * 64 + c]);
    float X1 = bf2f(xin[(base + 1) * 64 + c]);
    float X2 = bf2f(xin[(base + 2) * 64 + c]);
#pragma unroll 8
    for (int u = 0; u < 32; ++u) {
      float X3 = bf2f(xin[(base + u + 3) * 64 + c]);
      float v = cb + cw0 * X0 + cw1 * X1 + cw2 * X2 + cw3 * X3;
      unsigned short vh = f2bf(v);
      xcH[(base + u) * XP + c] = vh;
      xcL[(base + u) * XP + c] = f2bf(v - bf2f(vh));
      X0 = X1; X1 = X2; X2 = X3;
    }
  }
  // B fragments (wave-invariant, L1/L2-cached across blocks of same head)
  bf16x8 bIh[4][2], bIl[4][2], bAh[4][2], bAl[4][2];
#pragma unroll
  for (int nt = 0; nt < 4; ++nt)
#pragma unroll
    for (int ks = 0; ks < 2; ++ks) {
      size_t off = (size_t)h * 4096 + (size_t)(nt * 16 + fm) * 64 + ks * 32 + fq * 8;
      bIh[nt][ks] = *(const bf16x8*)(wiTH + off);
      bIl[nt][ks] = *(const bf16x8*)(wiTL + off);
      bAh[nt][ks] = *(const bf16x8*)(waTH + off);
      bAl[nt][ks] = *(const bf16x8*)(waTL + off);
    }
  f32x4 accI[2][4], accA[2][4];
#pragma unroll
  for (int mt = 0; mt < 2; ++mt)
#pragma unroll
    for (int nt = 0; nt < 4; ++nt) {
      accI[mt][nt] = f32x4{0.f, 0.f, 0.f, 0.f};
      accA[mt][nt] = f32x4{0.f, 0.f, 0.f, 0.f};
    }
  __syncthreads();
#pragma unroll
  for (int mt = 0; mt < 2; ++mt) {
    int mrow = wv * 32 + mt * 16 + fm;
#pragma unroll
    for (int ks = 0; ks < 2; ++ks) {
      bf16x8 ah = *(const bf16x8*)&xcH[mrow * XP + ks * 32 + fq * 8];
      bf16x8 al = *(const bf16x8*)&xcL[mrow * XP + ks * 32 + fq * 8];
#pragma unroll
      for (int nt = 0; nt < 4; ++nt) {
        accI[mt][nt] = __builtin_amdgcn_mfma_f32_16x16x32_bf16(ah, bIh[nt][ks], accI[mt][nt], 0, 0, 0);
        accI[mt][nt] = __builtin_amdgcn_mfma_f32_16x16x32_bf16(ah, bIl[nt][ks], accI[mt][nt], 0, 0, 0);
        accI[mt][nt] = __builtin_amdgcn_mfma_f32_16x16x32_bf16(al, bIh[nt][ks], accI[mt][nt], 0, 0, 0);
        accA[mt][nt] = __builtin_amdgcn_mfma_f32_16x16x32_bf16(ah, bAh[nt][ks], accA[mt][nt], 0, 0, 0);
        accA[mt][nt] = __builtin_amdgcn_mfma_f32_16x16x32_bf16(ah, bAl[nt][ks], accA[mt][nt], 0, 0, 0);
        accA[mt][nt] = __builtin_amdgcn_mfma_f32_16x16x32_bf16(al, bAh[nt][ks], accA[mt][nt], 0, 0, 0);
      }
    }
  }
  // epilogue: gates + transcendentals + writes
#pragma unroll
  for (int nt = 0; nt < 4; ++nt) {
    int colg = (h << 6) + nt * 16 + fm;
    float biv = bi[colg], bav = ba[colg];
    float apv = a_param[colg];
    float sp = (apv > 0.f) ? apv + log1pf(expf(-apv)) : log1pf(expf(apv));
#pragma unroll
    for (int mt = 0; mt < 2; ++mt) {
#pragma unroll
      for (int r = 0; r < 4; ++r) {
        int mrow = wv * 32 + mt * 16 + fq * 4 + r;
        int t = t0 + mrow;
        float xcv = bf2f(xcH[mrow * XP + nt * 16 + fm]) + bf2f(xcL[mrow * XP + nt * 16 + fm]);
        float gx = 1.0f / (1.0f + expf(-(accI[mt][nt][r] + biv)));
        float ga = 1.0f / (1.0f + expf(-(accA[mt][nt][r] + bav)));
        float la = -8.0f * ga * sp;
        float av = expf(la);
        float mult = sqrtf(fmaxf(-expm1f(2.0f * la), 0.0f));
        if (reset[b * 2048 + t]) { mult = 1.0f; av = 0.0f; }
        size_t idx = ((size_t)(b * 2048 + t) << 9) + colg;
        a_out[idx] = av;
        nrm[idx] = f2bf(xcv * gx * mult);
      }
    }
  }
}

// ---------------- chunked linear scan: 32 chunks of 64 steps
__global__ void scan1_kernel(const float* __restrict__ a, const unsigned short* __restrict__ nrm,
                             float* __restrict__ cA, float* __restrict__ cH) {
  int g = blockIdx.x * 256 + threadIdx.x;
  int c = g & 511, k = (g >> 9) & 31, b = g >> 14;
  size_t base = ((size_t)(b * 2048 + k * 64) << 9) + c;
  float A = 1.0f, h = 0.0f;
#pragma unroll 4
  for (int i = 0; i < 64; ++i) {
    float at = a[base + (size_t)i * 512];
    float nt = bf2f(nrm[base + (size_t)i * 512]);
    A *= at;
    h = fmaf(at, h, nt);
  }
  int ci = ((b * 32 + k) << 9) + c;
  cA[ci] = A;
  cH[ci] = h;
}

__global__ void scan2_kernel(const float* __restrict__ cA, const float* __restrict__ cH,
                             const float* __restrict__ h0, float* __restrict__ hinit) {
  int b = blockIdx.x, c = threadIdx.x;
  float h = h0[b * 512 + c];
  for (int k = 0; k < 32; ++k) {
    int ci = ((b * 32 + k) << 9) + c;
    hinit[ci] = h;
    h = fmaf(cA[ci], h, cH[ci]);
  }
}

__global__ void scan3_kernel(const float* __restrict__ a, const unsigned short* __restrict__ nrm,
                             const float* __restrict__ hinit, const unsigned short* __restrict__ ybuf,
                             unsigned short* __restrict__ p) {
  int g = blockIdx.x * 256 + threadIdx.x;
  int c = g & 511, k = (g >> 9) & 31, b = g >> 14;
  size_t base = ((size_t)(b * 2048 + k * 64) << 9) + c;
  int ci = ((b * 32 + k) << 9) + c;
  float h = hinit[ci];
#pragma unroll 4
  for (int i = 0; i < 64; ++i) {
    float at = a[base + (size_t)i * 512];
    float nt = bf2f(nrm[base + (size_t)i * 512]);
    h = fmaf(at, h, nt);
    float yv = bf2f(ybuf[base + (size_t)i * 512]);
    p[base + (size_t)i * 512] = f2bf(h * yv);
  }
}

// ---------------- GEMM2: out = p @ w_out + b_out (fp32 out)
__global__ __launch_bounds__(256, 2)
void gemm_out_kernel(const unsigned short* __restrict__ p,
                     const unsigned short* __restrict__ woT,
                     const float* __restrict__ bout, float* __restrict__ out) {
  __shared__ __align__(16) unsigned short As[128 * 32];
  __shared__ __align__(16) unsigned short Bs[128 * 32];
  const int tid = threadIdx.x, lane = tid & 63, wv = tid >> 6;
  const int m0 = blockIdx.y * 128, n0 = blockIdx.x * 128;
  const int sr = lane >> 2, sk = (lane & 3) * 8;
  const int wm = (wv >> 1) << 6, wn = (wv & 1) << 6;
  const int fm = lane & 15, fq = lane >> 4;

  f32x4 acc[4][4];
#pragma unroll
  for (int i = 0; i < 4; ++i)
#pragma unroll
    for (int j = 0; j < 4; ++j) acc[i][j] = f32x4{0.f, 0.f, 0.f, 0.f};

  const unsigned short* ga = p   + (size_t)(m0 + wv * 32 + sr) * 512 + sk;
  const unsigned short* gb = woT + (size_t)(n0 + wv * 32 + sr) * 512 + sk;
  unsigned short* lA = &As[wv * 32 * 32];
  unsigned short* lB = &Bs[wv * 32 * 32];

  for (int k0 = 0; k0 < 512; k0 += 32) {
    __syncthreads();
    gl2lds16(ga + k0,            lA);
    gl2lds16(ga + k0 + 16 * 512, lA + 16 * 32);
    gl2lds16(gb + k0,            lB);
    gl2lds16(gb + k0 + 16 * 512, lB + 16 * 32);
    __syncthreads();
    bf16x8 af[4], bfr[4];
#pragma unroll
    for (int i = 0; i < 4; ++i)
      af[i] = *(const bf16x8*)&As[(wm + i * 16 + fm) * 32 + fq * 8];
#pragma unroll
    for (int j = 0; j < 4; ++j)
      bfr[j] = *(const bf16x8*)&Bs[(wn + j * 16 + fm) * 32 + fq * 8];
#pragma unroll
    for (int i = 0; i < 4; ++i)
#pragma unroll
      for (int j = 0; j < 4; ++j)
        acc[i][j] = __builtin_amdgcn_mfma_f32_16x16x32_bf16(af[i], bfr[j], acc[i][j], 0, 0, 0);
  }
#pragma unroll
  for (int i = 0; i < 4; ++i) {
#pragma unroll
    for (int j = 0; j < 4; ++j) {
      int col = n0 + wn + j * 16 + fm;
      float bv = bout[col];
#pragma unroll
      for (int r = 0; r < 4; ++r) {
        int row = m0 + wm + i * 16 + fq * 4 + r;
        out[(size_t)row * 512 + col] = acc[i][j][r] + bv;
      }
    }
  }
}

extern "C" void kernel_launch(void* const* d_in, const int* in_sizes, int n_in,
                              void* d_out, int out_size, void* d_ws, size_t ws_size,
                              hipStream_t stream) {
  const float* x             = (const float*)d_in[0];
  const unsigned char* reset = (const unsigned char*)d_in[1];
  const float* h0            = (const float*)d_in[2];
  const float* b_x           = (const float*)d_in[4];
  const float* b_y           = (const float*)d_in[6];
  const float* conv_w        = (const float*)d_in[7];
  const float* conv_b        = (const float*)d_in[8];
  const float* a_param       = (const float*)d_in[9];
  const float* bi            = (const float*)d_in[11];
  const float* ba            = (const float*)d_in[13];
  const float* b_out         = (const float*)d_in[15];

  char* ws = (char*)d_ws;
  unsigned short* xbp  = (unsigned short*)(ws);               // 64MB bf16; reused as p after conv_gates
  unsigned short* ybuf = (unsigned short*)(ws + 64 * MBY);    // 64MB bf16
  float* a_arr         = (float*)(ws + 128 * MBY);            // 128MB fp32
  unsigned short* nrm  = (unsigned short*)(ws + 256 * MBY);   // 64MB bf16 (aliases xbf, dead after gemm_dual)
  unsigned short* xbf  = (unsigned short*)(ws + 256 * MBY);   // 64MB bf16 x input
  float* cA            = (float*)(ws + 320 * MBY);
  float* cH            = (float*)(ws + 322 * MBY);
  float* hinit         = (float*)(ws + 324 * MBY);
  unsigned short* wxT  = (unsigned short*)(ws + 326 * MBY);
  unsigned short* wyT  = (unsigned short*)(ws + 326 * MBY + 524288);
  unsigned short* woT  = (unsigned short*)(ws + 327 * MBY);
  unsigned short* wiTH = (unsigned short*)(ws + 327 * MBY + 524288);
  unsigned short* wiTL = wiTH + 65536 / 2;
  unsigned short* waTH = wiTL + 65536 / 2;
  unsigned short* waTL = waTH + 65536 / 2;
  unsigned short* p    = xbp;

  hipLaunchKernelGGL(prep_x_kernel, dim3(32768), dim3(256), 0, stream, x, xbf);
  hipLaunchKernelGGL(prep_wt_kernel, dim3(1024, 3), dim3(256), 0, stream,
                     (const float*)d_in[3], (const float*)d_in[5], (const float*)d_in[14],
                     wxT, wyT, woT);
  hipLaunchKernelGGL(prep_gatew_kernel, dim3(128), dim3(256), 0, stream,
                     (const float*)d_in[10], (const float*)d_in[12], wiTH, wiTL, waTH, waTL);
  hipLaunchKernelGGL(gemm_dual_kernel, dim3(4, 512), dim3(256), 0, stream,
                     xbf, wxT, wyT, b_x, b_y, xbp, ybuf);
  hipLaunchKernelGGL(conv_gates_kernel, dim3(16, 8, 32), dim3(256), 0, stream,
                     xbp, reset, conv_w, conv_b, a_param, wiTH, wiTL, waTH, waTL,
                     bi, ba, a_arr, nrm);
  hipLaunchKernelGGL(scan1_kernel, dim3(2048), dim3(256), 0, stream, a_arr, nrm, cA, cH);
  hipLaunchKernelGGL(scan2_kernel, dim3(32), dim3(512), 0, stream, cA, cH, h0, hinit);
  hipLaunchKernelGGL(scan3_kernel, dim3(2048), dim3(256), 0, stream, a_arr, nrm, hinit, ybuf, p);
  hipLaunchKernelGGL(gemm_out_kernel, dim3(4, 512), dim3(256), 0, stream, p, woT, b_out, (float*)d_out);
}

// Round 3
// 604.994 us; speedup vs baseline: 1.4846x; 1.2641x over previous
//
#include <hip/hip_runtime.h>

typedef __bf16 bf16x8 __attribute__((ext_vector_type(8)));
typedef float f32x4 __attribute__((ext_vector_type(4)));
typedef unsigned short u16x8 __attribute__((ext_vector_type(8)));
typedef unsigned short u16x4 __attribute__((ext_vector_type(4)));

#define MBY (1ull << 20)

__device__ __forceinline__ unsigned short f2bf(float f) {
  union { float f; unsigned u; } v; v.f = f;
  unsigned r = v.u + 0x7fffu + ((v.u >> 16) & 1u);  // RNE
  return (unsigned short)(r >> 16);
}
__device__ __forceinline__ float bf2f(unsigned short s) {
  union { unsigned u; float f; } v; v.u = ((unsigned)s) << 16;
  return v.f;
}
__device__ __forceinline__ float fexp(float x) {        // native v_exp_f32
  return __builtin_amdgcn_exp2f(x * 1.44269504088896340736f);
}
__device__ __forceinline__ float frcp(float x) {        // native v_rcp_f32 (~1 ulp)
  return __builtin_amdgcn_rcpf(x);
}
// async global->LDS, 16B per lane; lds dest = wave-uniform base + lane*16
__device__ __forceinline__ void gl2lds16(const void* g, void* l) {
  __builtin_amdgcn_global_load_lds(
      (const __attribute__((address_space(1))) unsigned int*)g,
      (__attribute__((address_space(3))) unsigned int*)l, 16, 0, 0);
}

// ---------------- prep: x -> bf16
__global__ void prep_x_kernel(const float* __restrict__ x, unsigned short* __restrict__ xbf) {
  int g = blockIdx.x * 256 + threadIdx.x;
  float4 v = ((const float4*)x)[g];
  u16x4 o;
  o[0] = f2bf(v.x); o[1] = f2bf(v.y); o[2] = f2bf(v.z); o[3] = f2bf(v.w);
  *(u16x4*)(xbf + (size_t)g * 4) = o;
}

// ---------------- prep: weight transposes + gate hi/lo split + softplus table
__global__ void prep_misc_kernel(const float* __restrict__ wx, const float* __restrict__ wy,
                                 const float* __restrict__ wo,
                                 const float* __restrict__ wi, const float* __restrict__ wa,
                                 const float* __restrict__ a_param,
                                 unsigned short* __restrict__ wxT, unsigned short* __restrict__ wyT,
                                 unsigned short* __restrict__ woT,
                                 unsigned short* __restrict__ wiTH, unsigned short* __restrict__ wiTL,
                                 unsigned short* __restrict__ waTH, unsigned short* __restrict__ waTL,
                                 float* __restrict__ spbuf) {
  int bid = blockIdx.x, tid = threadIdx.x;
  if (bid < 3072) {                       // 3 big weights: transpose+bf16
    int mat = bid >> 10;
    int g = (bid & 1023) * 256 + tid;
    int n = g & 511, k = g >> 9;
    const float* src = (mat == 0) ? wx : (mat == 1) ? wy : wo;
    unsigned short* dst = (mat == 0) ? wxT : (mat == 1) ? wyT : woT;
    dst[(size_t)n * 512 + k] = f2bf(src[(size_t)k * 512 + n]);
  } else if (bid < 3200) {                // gate weights: transposed hi/lo split
    int g = (bid - 3072) * 256 + tid;
    int j = g & 63, i = (g >> 6) & 63, h = g >> 12;
    size_t src = (size_t)h * 4096 + (size_t)i * 64 + j;
    size_t dst = (size_t)h * 4096 + (size_t)j * 64 + i;
    float v = wi[src];
    unsigned short hh = f2bf(v);
    wiTH[dst] = hh; wiTL[dst] = f2bf(v - bf2f(hh));
    v = wa[src];
    hh = f2bf(v);
    waTH[dst] = hh; waTL[dst] = f2bf(v - bf2f(hh));
  } else {                                // softplus(a_param) table (accurate, once)
    int g = (bid - 3200) * 256 + tid;
    if (g < 512) {
      float ap = a_param[g];
      spbuf[g] = (ap > 0.f) ? ap + log1pf(expf(-ap)) : log1pf(expf(ap));
    }
  }
}

// ---------------- GEMM1 (dual): xb_pre = x@w_x + b_x ; yb = gelu(x@w_y + b_y)
__global__ __launch_bounds__(256, 2)
void gemm_dual_kernel(const unsigned short* __restrict__ xbf,
                      const unsigned short* __restrict__ wxT,
                      const unsigned short* __restrict__ wyT,
                      const float* __restrict__ bx, const float* __restrict__ by,
                      unsigned short* __restrict__ xbp, unsigned short* __restrict__ ybuf) {
  __shared__ __align__(16) unsigned short As[128 * 32];
  __shared__ __align__(16) unsigned short Bs0[128 * 32];
  __shared__ __align__(16) unsigned short Bs1[128 * 32];
  const int tid = threadIdx.x, lane = tid & 63, wv = tid >> 6;
  const int m0 = blockIdx.y * 128, n0 = blockIdx.x * 128;
  const int sr = lane >> 2, sk = (lane & 3) * 8;
  const int wm = (wv >> 1) << 6, wn = (wv & 1) << 6;
  const int fm = lane & 15, fq = lane >> 4;

  f32x4 acc0[4][4], acc1[4][4];
#pragma unroll
  for (int i = 0; i < 4; ++i)
#pragma unroll
    for (int j = 0; j < 4; ++j) {
      acc0[i][j] = f32x4{0.f, 0.f, 0.f, 0.f};
      acc1[i][j] = f32x4{0.f, 0.f, 0.f, 0.f};
    }

  const unsigned short* ga  = xbf + (size_t)(m0 + wv * 32 + sr) * 512 + sk;
  const unsigned short* gb0 = wxT + (size_t)(n0 + wv * 32 + sr) * 512 + sk;
  const unsigned short* gb1 = wyT + (size_t)(n0 + wv * 32 + sr) * 512 + sk;
  unsigned short* lA  = &As [wv * 32 * 32];
  unsigned short* lB0 = &Bs0[wv * 32 * 32];
  unsigned short* lB1 = &Bs1[wv * 32 * 32];

  for (int k0 = 0; k0 < 512; k0 += 32) {
    __syncthreads();
    gl2lds16(ga  + k0,            lA);
    gl2lds16(ga  + k0 + 16 * 512, lA  + 16 * 32);
    gl2lds16(gb0 + k0,            lB0);
    gl2lds16(gb0 + k0 + 16 * 512, lB0 + 16 * 32);
    gl2lds16(gb1 + k0,            lB1);
    gl2lds16(gb1 + k0 + 16 * 512, lB1 + 16 * 32);
    __syncthreads();
    bf16x8 af[4], bfr0[4], bfr1[4];
#pragma unroll
    for (int i = 0; i < 4; ++i)
      af[i] = *(const bf16x8*)&As[(wm + i * 16 + fm) * 32 + fq * 8];
#pragma unroll
    for (int j = 0; j < 4; ++j) {
      bfr0[j] = *(const bf16x8*)&Bs0[(wn + j * 16 + fm) * 32 + fq * 8];
      bfr1[j] = *(const bf16x8*)&Bs1[(wn + j * 16 + fm) * 32 + fq * 8];
    }
#pragma unroll
    for (int i = 0; i < 4; ++i)
#pragma unroll
      for (int j = 0; j < 4; ++j) {
        acc0[i][j] = __builtin_amdgcn_mfma_f32_16x16x32_bf16(af[i], bfr0[j], acc0[i][j], 0, 0, 0);
        acc1[i][j] = __builtin_amdgcn_mfma_f32_16x16x32_bf16(af[i], bfr1[j], acc1[i][j], 0, 0, 0);
      }
  }
#pragma unroll
  for (int i = 0; i < 4; ++i) {
#pragma unroll
    for (int j = 0; j < 4; ++j) {
      int col = n0 + wn + j * 16 + fm;
      float bxv = bx[col], byv = by[col];
#pragma unroll
      for (int r = 0; r < 4; ++r) {
        int row = m0 + wm + i * 16 + fq * 4 + r;
        size_t idx = (size_t)row * 512 + col;
        xbp[idx] = f2bf(acc0[i][j][r] + bxv);
        float z = acc1[i][j][r] + byv;
        float zc = 0.7978845608028654f * (z + 0.044715f * z * z * z);
        float e = fexp(2.0f * zc);                       // fast tanh: 1 - 2/(e^{2t}+1)
        float th = 1.0f - 2.0f * frcp(e + 1.0f);
        ybuf[idx] = f2bf(0.5f * z * (1.0f + th));
      }
    }
  }
}

// ---------------- conv (TW=4) + MFMA gate GEMMs + fast-math epilogue
#define XP 72
__global__ __launch_bounds__(256, 2)
void conv_gates_kernel(const unsigned short* __restrict__ xbp,
                       const unsigned char* __restrict__ reset,
                       const float* __restrict__ conv_w, const float* __restrict__ conv_b,
                       const float* __restrict__ spbuf,
                       const unsigned short* __restrict__ wiTH, const unsigned short* __restrict__ wiTL,
                       const unsigned short* __restrict__ waTH, const unsigned short* __restrict__ waTL,
                       const float* __restrict__ bi, const float* __restrict__ ba,
                       unsigned short* __restrict__ aq_out, unsigned short* __restrict__ nrm) {
  __shared__ __align__(16) unsigned short xin[131 * 64];
  __shared__ __align__(16) unsigned short xcH[128 * XP];
  __shared__ __align__(16) unsigned short xcL[128 * XP];
  const int tile = blockIdx.x, h = blockIdx.y, b = blockIdx.z;
  const int t0 = tile << 7;
  const int tid = threadIdx.x, lane = tid & 63, wv = tid >> 6;
  const int fm = lane & 15, fq = lane >> 4;

  // vectorized staging: 131 rows x 64 ch = 1048 u16x8 groups
  const size_t cb0 = ((size_t)b * 2048) * 512 + (h << 6);
  for (int idx = tid; idx < 1048; idx += 256) {
    int row = idx >> 3, c8 = (idx & 7) << 3;
    int t = t0 - 3 + row;
    u16x8 v = u16x8{0, 0, 0, 0, 0, 0, 0, 0};
    if (t >= 0) v = *(const u16x8*)(xbp + cb0 + (size_t)t * 512 + c8);
    *(u16x8*)&xin[row * 64 + c8] = v;
  }
  __syncthreads();
  // vectorized conv in fp32 -> hi/lo bf16 planes
  {
    const int c8 = (tid & 7) << 3, u0 = tid >> 3;
    const int ch8 = (h << 6) + c8;
    float cw[4][8], cbv[8];
#pragma unroll
    for (int s = 0; s < 4; ++s) {
      *(float4*)&cw[s][0] = *(const float4*)(conv_w + s * 512 + ch8);
      *(float4*)&cw[s][4] = *(const float4*)(conv_w + s * 512 + ch8 + 4);
    }
    *(float4*)&cbv[0] = *(const float4*)(conv_b + ch8);
    *(float4*)&cbv[4] = *(const float4*)(conv_b + ch8 + 4);
#pragma unroll
    for (int g = 0; g < 4; ++g) {
      int u = u0 + g * 32;
      u16x8 r0 = *(const u16x8*)&xin[(u + 0) * 64 + c8];
      u16x8 r1 = *(const u16x8*)&xin[(u + 1) * 64 + c8];
      u16x8 r2 = *(const u16x8*)&xin[(u + 2) * 64 + c8];
      u16x8 r3 = *(const u16x8*)&xin[(u + 3) * 64 + c8];
      u16x8 oh, ol;
#pragma unroll
      for (int j = 0; j < 8; ++j) {
        float v = cbv[j] + cw[0][j] * bf2f(r0[j]) + cw[1][j] * bf2f(r1[j]) +
                  cw[2][j] * bf2f(r2[j]) + cw[3][j] * bf2f(r3[j]);
        oh[j] = f2bf(v);
        ol[j] = f2bf(v - bf2f(oh[j]));
      }
      *(u16x8*)&xcH[u * XP + c8] = oh;
      *(u16x8*)&xcL[u * XP + c8] = ol;
    }
  }
  // B fragments (wave-invariant, cached)
  bf16x8 bIh[4][2], bIl[4][2], bAh[4][2], bAl[4][2];
#pragma unroll
  for (int nt = 0; nt < 4; ++nt)
#pragma unroll
    for (int ks = 0; ks < 2; ++ks) {
      size_t off = (size_t)h * 4096 + (size_t)(nt * 16 + fm) * 64 + ks * 32 + fq * 8;
      bIh[nt][ks] = *(const bf16x8*)(wiTH + off);
      bIl[nt][ks] = *(const bf16x8*)(wiTL + off);
      bAh[nt][ks] = *(const bf16x8*)(waTH + off);
      bAl[nt][ks] = *(const bf16x8*)(waTL + off);
    }
  f32x4 accI[2][4], accA[2][4];
#pragma unroll
  for (int mt = 0; mt < 2; ++mt)
#pragma unroll
    for (int nt = 0; nt < 4; ++nt) {
      accI[mt][nt] = f32x4{0.f, 0.f, 0.f, 0.f};
      accA[mt][nt] = f32x4{0.f, 0.f, 0.f, 0.f};
    }
  __syncthreads();
#pragma unroll
  for (int mt = 0; mt < 2; ++mt) {
    int mrow = wv * 32 + mt * 16 + fm;
#pragma unroll
    for (int ks = 0; ks < 2; ++ks) {
      bf16x8 ah = *(const bf16x8*)&xcH[mrow * XP + ks * 32 + fq * 8];
      bf16x8 al = *(const bf16x8*)&xcL[mrow * XP + ks * 32 + fq * 8];
#pragma unroll
      for (int nt = 0; nt < 4; ++nt) {
        accI[mt][nt] = __builtin_amdgcn_mfma_f32_16x16x32_bf16(ah, bIh[nt][ks], accI[mt][nt], 0, 0, 0);
        accI[mt][nt] = __builtin_amdgcn_mfma_f32_16x16x32_bf16(ah, bIl[nt][ks], accI[mt][nt], 0, 0, 0);
        accI[mt][nt] = __builtin_amdgcn_mfma_f32_16x16x32_bf16(al, bIh[nt][ks], accI[mt][nt], 0, 0, 0);
        accA[mt][nt] = __builtin_amdgcn_mfma_f32_16x16x32_bf16(ah, bAh[nt][ks], accA[mt][nt], 0, 0, 0);
        accA[mt][nt] = __builtin_amdgcn_mfma_f32_16x16x32_bf16(ah, bAl[nt][ks], accA[mt][nt], 0, 0, 0);
        accA[mt][nt] = __builtin_amdgcn_mfma_f32_16x16x32_bf16(al, bAh[nt][ks], accA[mt][nt], 0, 0, 0);
      }
    }
  }
  // epilogue: all-native-transcendental
#pragma unroll
  for (int nt = 0; nt < 4; ++nt) {
    int colg = (h << 6) + nt * 16 + fm;
    float biv = bi[colg], bav = ba[colg];
    float sp8 = -8.0f * spbuf[colg];
#pragma unroll
    for (int mt = 0; mt < 2; ++mt) {
#pragma unroll
      for (int r = 0; r < 4; ++r) {
        int mrow = wv * 32 + mt * 16 + fq * 4 + r;
        int t = t0 + mrow;
        float xcv = bf2f(xcH[mrow * XP + nt * 16 + fm]) + bf2f(xcL[mrow * XP + nt * 16 + fm]);
        float gx = frcp(1.0f + fexp(-(accI[mt][nt][r] + biv)));
        float ga = frcp(1.0f + fexp(-(accA[mt][nt][r] + bav)));
        float la = sp8 * ga;
        float av = fexp(la);
        float mult = __builtin_amdgcn_sqrtf(fmaxf(1.0f - fexp(2.0f * la), 0.0f));
        if (reset[b * 2048 + t]) { mult = 1.0f; av = 0.0f; }
        size_t idx = ((size_t)(b * 2048 + t)) * 512 + colg;
        aq_out[idx] = (unsigned short)fminf(av * 65536.0f + 0.5f, 65535.0f);
        nrm[idx] = f2bf(xcv * gx * mult);
      }
    }
  }
}

// ---------------- chunked linear scan (a as u16 fixed-point, 4 ch/thread)
__global__ void scan1_kernel(const unsigned short* __restrict__ aq, const unsigned short* __restrict__ nrm,
                             float* __restrict__ cA, float* __restrict__ cH) {
  int g = blockIdx.x * 256 + threadIdx.x;  // 131072
  int c4 = (g & 127) << 2, k = (g >> 7) & 31, b = g >> 12;
  size_t base = ((size_t)(b * 2048 + k * 64)) * 512 + c4;
  float A[4] = {1.f, 1.f, 1.f, 1.f}, h[4] = {0.f, 0.f, 0.f, 0.f};
#pragma unroll 4
  for (int i = 0; i < 64; ++i) {
    u16x4 av = *(const u16x4*)(aq + base + (size_t)i * 512);
    u16x4 nv = *(const u16x4*)(nrm + base + (size_t)i * 512);
#pragma unroll
    for (int j = 0; j < 4; ++j) {
      float a = (float)av[j] * (1.0f / 65536.0f);
      A[j] *= a;
      h[j] = fmaf(a, h[j], bf2f(nv[j]));
    }
  }
  int ci = ((b * 32 + k) << 9) + c4;
#pragma unroll
  for (int j = 0; j < 4; ++j) { cA[ci + j] = A[j]; cH[ci + j] = h[j]; }
}

__global__ void scan2_kernel(const float* __restrict__ cA, const float* __restrict__ cH,
                             const float* __restrict__ h0, float* __restrict__ hinit) {
  int b = blockIdx.x, c = threadIdx.x;
  float h = h0[b * 512 + c];
  for (int k = 0; k < 32; ++k) {
    int ci = ((b * 32 + k) << 9) + c;
    hinit[ci] = h;
    h = fmaf(cA[ci], h, cH[ci]);
  }
}

__global__ void scan3_kernel(const unsigned short* __restrict__ aq, const unsigned short* __restrict__ nrm,
                             const float* __restrict__ hinit, const unsigned short* __restrict__ ybuf,
                             unsigned short* __restrict__ p) {
  int g = blockIdx.x * 256 + threadIdx.x;  // 131072
  int c4 = (g & 127) << 2, k = (g >> 7) & 31, b = g >> 12;
  size_t base = ((size_t)(b * 2048 + k * 64)) * 512 + c4;
  int ci = ((b * 32 + k) << 9) + c4;
  float h[4];
#pragma unroll
  for (int j = 0; j < 4; ++j) h[j] = hinit[ci + j];
#pragma unroll 4
  for (int i = 0; i < 64; ++i) {
    u16x4 av = *(const u16x4*)(aq + base + (size_t)i * 512);
    u16x4 nv = *(const u16x4*)(nrm + base + (size_t)i * 512);
    u16x4 yv = *(const u16x4*)(ybuf + base + (size_t)i * 512);
    u16x4 pv;
#pragma unroll
    for (int j = 0; j < 4; ++j) {
      float a = (float)av[j] * (1.0f / 65536.0f);
      h[j] = fmaf(a, h[j], bf2f(nv[j]));
      pv[j] = f2bf(h[j] * bf2f(yv[j]));
    }
    *(u16x4*)(p + base + (size_t)i * 512) = pv;
  }
}

// ---------------- GEMM2: out = p @ w_out + b_out (fp32 out)
__global__ __launch_bounds__(256, 2)
void gemm_out_kernel(const unsigned short* __restrict__ p,
                     const unsigned short* __restrict__ woT,
                     const float* __restrict__ bout, float* __restrict__ out) {
  __shared__ __align__(16) unsigned short As[128 * 32];
  __shared__ __align__(16) unsigned short Bs[128 * 32];
  const int tid = threadIdx.x, lane = tid & 63, wv = tid >> 6;
  const int m0 = blockIdx.y * 128, n0 = blockIdx.x * 128;
  const int sr = lane >> 2, sk = (lane & 3) * 8;
  const int wm = (wv >> 1) << 6, wn = (wv & 1) << 6;
  const int fm = lane & 15, fq = lane >> 4;

  f32x4 acc[4][4];
#pragma unroll
  for (int i = 0; i < 4; ++i)
#pragma unroll
    for (int j = 0; j < 4; ++j) acc[i][j] = f32x4{0.f, 0.f, 0.f, 0.f};

  const unsigned short* ga = p   + (size_t)(m0 + wv * 32 + sr) * 512 + sk;
  const unsigned short* gb = woT + (size_t)(n0 + wv * 32 + sr) * 512 + sk;
  unsigned short* lA = &As[wv * 32 * 32];
  unsigned short* lB = &Bs[wv * 32 * 32];

  for (int k0 = 0; k0 < 512; k0 += 32) {
    __syncthreads();
    gl2lds16(ga + k0,            lA);
    gl2lds16(ga + k0 + 16 * 512, lA + 16 * 32);
    gl2lds16(gb + k0,            lB);
    gl2lds16(gb + k0 + 16 * 512, lB + 16 * 32);
    __syncthreads();
    bf16x8 af[4], bfr[4];
#pragma unroll
    for (int i = 0; i < 4; ++i)
      af[i] = *(const bf16x8*)&As[(wm + i * 16 + fm) * 32 + fq * 8];
#pragma unroll
    for (int j = 0; j < 4; ++j)
      bfr[j] = *(const bf16x8*)&Bs[(wn + j * 16 + fm) * 32 + fq * 8];
#pragma unroll
    for (int i = 0; i < 4; ++i)
#pragma unroll
      for (int j = 0; j < 4; ++j)
        acc[i][j] = __builtin_amdgcn_mfma_f32_16x16x32_bf16(af[i], bfr[j], acc[i][j], 0, 0, 0);
  }
#pragma unroll
  for (int i = 0; i < 4; ++i) {
#pragma unroll
    for (int j = 0; j < 4; ++j) {
      int col = n0 + wn + j * 16 + fm;
      float bv = bout[col];
#pragma unroll
      for (int r = 0; r < 4; ++r) {
        int row = m0 + wm + i * 16 + fq * 4 + r;
        out[(size_t)row * 512 + col] = acc[i][j][r] + bv;
      }
    }
  }
}

extern "C" void kernel_launch(void* const* d_in, const int* in_sizes, int n_in,
                              void* d_out, int out_size, void* d_ws, size_t ws_size,
                              hipStream_t stream) {
  const float* x             = (const float*)d_in[0];
  const unsigned char* reset = (const unsigned char*)d_in[1];
  const float* h0            = (const float*)d_in[2];
  const float* b_x           = (const float*)d_in[4];
  const float* b_y           = (const float*)d_in[6];
  const float* conv_w        = (const float*)d_in[7];
  const float* conv_b        = (const float*)d_in[8];
  const float* bi            = (const float*)d_in[11];
  const float* ba            = (const float*)d_in[13];
  const float* b_out         = (const float*)d_in[15];

  char* ws = (char*)d_ws;
  unsigned short* xbp  = (unsigned short*)(ws);               // 64MB bf16; reused as p
  unsigned short* ybuf = (unsigned short*)(ws + 64 * MBY);    // 64MB bf16
  unsigned short* aq   = (unsigned short*)(ws + 128 * MBY);   // 64MB u16 fixed-point a
  unsigned short* nrm  = (unsigned short*)(ws + 192 * MBY);   // 64MB bf16 (aliases xbf)
  unsigned short* xbf  = (unsigned short*)(ws + 192 * MBY);   // 64MB bf16 x
  float* cA            = (float*)(ws + 256 * MBY);
  float* cH            = (float*)(ws + 258 * MBY);
  float* hinit         = (float*)(ws + 260 * MBY);
  unsigned short* wxT  = (unsigned short*)(ws + 262 * MBY);
  unsigned short* wyT  = (unsigned short*)(ws + 262 * MBY + 524288);
  unsigned short* woT  = (unsigned short*)(ws + 263 * MBY);
  unsigned short* wiTH = (unsigned short*)(ws + 263 * MBY + 524288);
  unsigned short* wiTL = wiTH + 32768;
  unsigned short* waTH = wiTL + 32768;
  unsigned short* waTL = waTH + 32768;
  float* spbuf         = (float*)(waTL + 32768);
  unsigned short* p    = xbp;

  hipLaunchKernelGGL(prep_x_kernel, dim3(32768), dim3(256), 0, stream, x, xbf);
  hipLaunchKernelGGL(prep_misc_kernel, dim3(3202), dim3(256), 0, stream,
                     (const float*)d_in[3], (const float*)d_in[5], (const float*)d_in[14],
                     (const float*)d_in[10], (const float*)d_in[12], (const float*)d_in[9],
                     wxT, wyT, woT, wiTH, wiTL, waTH, waTL, spbuf);
  hipLaunchKernelGGL(gemm_dual_kernel, dim3(4, 512), dim3(256), 0, stream,
                     xbf, wxT, wyT, b_x, b_y, xbp, ybuf);
  hipLaunchKernelGGL(conv_gates_kernel, dim3(16, 8, 32), dim3(256), 0, stream,
                     xbp, reset, conv_w, conv_b, spbuf, wiTH, wiTL, waTH, waTL,
                     bi, ba, aq, nrm);
  hipLaunchKernelGGL(scan1_kernel, dim3(512), dim3(256), 0, stream, aq, nrm, cA, cH);
  hipLaunchKernelGGL(scan2_kernel, dim3(32), dim3(512), 0, stream, cA, cH, h0, hinit);
  hipLaunchKernelGGL(scan3_kernel, dim3(512), dim3(256), 0, stream, aq, nrm, hinit, ybuf, p);
  hipLaunchKernelGGL(gemm_out_kernel, dim3(4, 512), dim3(256), 0, stream, p, woT, b_out, (float*)d_out);
}